// Round 9
// baseline (139.902 us; speedup 1.0000x reference)
//
#include <hip/hip_runtime.h>

// Modulated deformable conv2d, fp32 in/out, bf16 MFMA core.
// B=4, C=64, H=W=128, O=64, K=3x3, stride=1, pad=1, dil=1, og=1, groups=1.
//
// Round 9: cache-level stream separation. Five structural variants (r5-r8)
// all plateau at 45-52 us with MfmaUtil ~3.4% / VALUBusy ~27%: the wall is
// the CU L1 fill port, thrashed by TWO equal ~295 MB streams: (a) scattered
// corner gathers (always-miss, 2 KB refill per 1 KB used) and (b) weight
// fragments re-streamed by every wave every tap (should be L1-resident but
// get evicted by (a)). Fix: corner loads use __builtin_nontemporal_load ->
// no L1 allocation; L1 then keeps the 8 KB/tap weight fragments hot for all
// resident waves. Structure otherwise = round 7 (2048 blocks x 4 waves =
// 2 pixel-strips x 2 channel-halves; end-of-kernel LDS reduction; round-8's
// software pipeline was proven neutral and is dropped).
// Fragment layouts (m89/m120-verified): A[m=lane&15][k=quad*8+j],
// B[k=quad*8+j][n=lane&15], D[row=quad*4+reg][col=lane&15].

#define BB 4
#define CC 64
#define HH 128
#define WW 128
#define OO 64
#define KHW 3
#define KK 9
#define HW (HH * WW)

typedef __bf16 bf16_t;
typedef bf16_t bf16x8 __attribute__((ext_vector_type(8)));
typedef float f32x4 __attribute__((ext_vector_type(4)));

// ---- x (NCHW fp32) -> xt (NHWC bf16), LDS-tiled transpose ----
__global__ __launch_bounds__(256) void nhwc_kernel(const float* __restrict__ x,
                                                   bf16_t* __restrict__ xt) {
    __shared__ float tile[64 * 65];
    const int t  = threadIdx.x;
    const int b  = blockIdx.x >> 8;
    const int p0 = (blockIdx.x & 255) << 6;
#pragma unroll
    for (int i = 0; i < 16; ++i) {
        int c = i * 4 + (t >> 6);
        int p = t & 63;
        tile[c * 65 + p] = x[(b * CC + c) * HW + p0 + p];  // coalesced read
    }
    __syncthreads();
#pragma unroll
    for (int i = 0; i < 16; ++i) {
        int p = i * 4 + (t >> 6);
        int c = t & 63;
        xt[(size_t)((b * HW) + p0 + p) * CC + c] = (bf16_t)tile[c * 65 + p];
    }
}

// ---- weight [O][C][3][3] fp32 -> B-fragment order bf16 ----
// wf element index: ((tap*2+q)*4+nt)*64*8 + lane*8 + j
//   holds W[o = nt*16 + (lane&15)][c = q*32 + (lane>>4)*8 + j][tap]
__global__ void wfrag_kernel(const float* __restrict__ w,
                             bf16_t* __restrict__ wf) {
    int i = blockIdx.x * blockDim.x + threadIdx.x;
    if (i >= OO * CC * KK) return;
    int j    = i & 7;
    int lane = (i >> 3) & 63;
    int nt   = (i >> 9) & 3;
    int q    = (i >> 11) & 1;
    int k    = i >> 12;
    int o = nt * 16 + (lane & 15);
    int c = q * 32 + ((lane >> 4) << 3) + j;
    wf[i] = (bf16_t)w[(o * CC + c) * KK + k];
}

__global__ __launch_bounds__(256, 4) void deform_conv_mfma(
    const bf16_t* __restrict__ xt, const float* __restrict__ offset,
    const float* __restrict__ mask, const bf16x8* __restrict__ wf,
    const float* __restrict__ bias, float* __restrict__ out) {
    const int t     = threadIdx.x;
    const int lane  = t & 63;
    const int wv    = t >> 6;
    const int strip = wv & 1;                  // which 16-pixel strip
    const int half  = wv >> 1;                 // which 32-channel half
    const int b     = blockIdx.x >> 9;         // 512 blocks per image
    const int p0    = (blockIdx.x & 511) << 5; // block's 32-pixel group
    const int m0    = strip << 4;
    const int col   = lane & 15;
    const int quad  = lane >> 4;

    // This lane samples pixel (p0+m0+col), channels half*32 + quad*8 .. +8
    // -- exactly its A-fragment slots for K-chunk `half`.
    const int rem = p0 + m0 + col;
    const int ho  = rem >> 7;
    const int wo  = rem & (WW - 1);
    const int cb  = (half << 5) + (quad << 3);

    const bf16_t* xb = xt + (size_t)b * HW * CC;

    __shared__ f32x4 red[2][4][64];            // [strip][nt][lane], 8 KB

    f32x4 acc[4];
#pragma unroll
    for (int nt = 0; nt < 4; ++nt) acc[nt] = (f32x4){0.f, 0.f, 0.f, 0.f};

    const int offbase = (b * (2 * KK)) * HW + rem;
    const int mbase   = (b * KK) * HW + rem;

    for (int k = 0; k < KK; ++k) {
        float offy = offset[offbase + (2 * k) * HW];
        float offx = offset[offbase + (2 * k + 1) * HW];
        float mm   = mask[mbase + k * HW];
        float py = offy + (float)(k / KHW) + (float)(ho - 1);
        float px = offx + (float)(k % KHW) + (float)(wo - 1);
        float fy0 = floorf(py), fx0 = floorf(px);
        float ly = py - fy0, lx = px - fx0;
        int y0 = (int)fy0, x0 = (int)fx0;
        int y1 = y0 + 1, x1 = x0 + 1;
        bool vy0 = (y0 >= 0) && (y0 < HH);
        bool vy1 = (y1 >= 0) && (y1 < HH);
        bool vx0 = (x0 >= 0) && (x0 < WW);
        bool vx1 = (x1 >= 0) && (x1 < WW);
        int cy0 = min(max(y0, 0), HH - 1), cy1 = min(max(y1, 0), HH - 1);
        int cx0 = min(max(x0, 0), WW - 1), cx1 = min(max(x1, 0), WW - 1);
        float w0 = (vy0 && vx0) ? mm * (1.0f - ly) * (1.0f - lx) : 0.0f;
        float w1 = (vy0 && vx1) ? mm * (1.0f - ly) * lx : 0.0f;
        float w2 = (vy1 && vx0) ? mm * ly * (1.0f - lx) : 0.0f;
        float w3 = (vy1 && vx1) ? mm * ly * lx : 0.0f;

        // 4 corner loads, 16B each, NON-TEMPORAL: bypass L1 allocation so
        // the weight-fragment stream below stays L1-resident. Corner reuse
        // lives in L2 (whole 2 MB image fits per XCD).
        bf16x8 a0 = __builtin_nontemporal_load(
            (const bf16x8*)(xb + (cy0 * WW + cx0) * CC + cb));
        bf16x8 a1 = __builtin_nontemporal_load(
            (const bf16x8*)(xb + (cy0 * WW + cx1) * CC + cb));
        bf16x8 a2 = __builtin_nontemporal_load(
            (const bf16x8*)(xb + (cy1 * WW + cx0) * CC + cb));
        bf16x8 a3 = __builtin_nontemporal_load(
            (const bf16x8*)(xb + (cy1 * WW + cx1) * CC + cb));

        bf16x8 af;
#pragma unroll
        for (int i = 0; i < 8; ++i) {
            float v = w0 * (float)a0[i] + w1 * (float)a1[i] +
                      w2 * (float)a2[i] + w3 * (float)a3[i];
            af[i] = (bf16_t)v;
        }

        const bf16x8* wk = wf + (size_t)((k * 2 + half) * 4) * 64;
#pragma unroll
        for (int nt = 0; nt < 4; ++nt) {
            bf16x8 bfr = wk[nt * 64 + lane];   // L1-resident (8 KB per tap)
            acc[nt] = __builtin_amdgcn_mfma_f32_16x16x32_bf16(af, bfr, acc[nt],
                                                              0, 0, 0);
        }
    }

    // ---- combine channel-halves, then epilogue from half==0 waves ----
    if (half == 1) {
#pragma unroll
        for (int nt = 0; nt < 4; ++nt) red[strip][nt][lane] = acc[nt];
    }
    __syncthreads();
    if (half == 0) {
#pragma unroll
        for (int nt = 0; nt < 4; ++nt) {
            int o = nt * 16 + col;
            float bv = bias[o];
            f32x4 r = acc[nt] + red[strip][nt][lane];
            r.x += bv; r.y += bv; r.z += bv; r.w += bv;
            // D[row=quad*4+reg][col]; row -> pixel, col -> output channel.
            float* dst = out + (size_t)(b * OO + o) * HW + p0 + m0 + quad * 4;
            *(f32x4*)dst = r;  // 4 consecutive pixels, 16B aligned
        }
    }
}

extern "C" void kernel_launch(void* const* d_in, const int* in_sizes, int n_in,
                              void* d_out, int out_size, void* d_ws,
                              size_t ws_size, hipStream_t stream) {
    const float* x      = (const float*)d_in[0];
    const float* offset = (const float*)d_in[1];
    const float* mask   = (const float*)d_in[2];
    const float* weight = (const float*)d_in[3];
    const float* bias   = (const float*)d_in[4];
    float* out = (float*)d_out;

    bf16_t* xt  = (bf16_t*)d_ws;                      // 4*16384*64*2 = 8 MB
    bf16_t* wfr = (bf16_t*)((char*)d_ws + (size_t)BB * HW * CC * 2);  // 72 KB

    nhwc_kernel<<<BB * (HW / 64), 256, 0, stream>>>(x, xt);

    int nw = OO * CC * KK;  // 36864
    wfrag_kernel<<<(nw + 255) / 256, 256, 0, stream>>>(weight, wfr);

    deform_conv_mfma<<<BB * (HW / 32), 256, 0, stream>>>(
        xt, offset, mask, (const bf16x8*)wfr, bias, out);
}

// Round 10
// 124.583 us; speedup vs baseline: 1.1230x; 1.1230x over previous
//
#include <hip/hip_runtime.h>

// Modulated deformable conv2d, fp32 in/out, bf16 MFMA core.
// B=4, C=64, H=W=128, O=64, K=3x3, stride=1, pad=1, dil=1, og=1, groups=1.
//
// Round 10: batched-gather MLP. r5-r9 (five structures) all pin at 45-52 us,
// VALUBusy ~27%, MfmaUtil ~3.4%: per-wave SERIAL tap chains dominate; the
// compiler sinks rotated prefetches (r8, VGPR 44). Fix: (a) preload all 27
// offset/mask scalars at entry; (b) 3 batches x 3 taps: addr calc (VALU only)
// -> 12 int-offset gathers issued back-to-back -> consume. All uses follow
// all loads in a batch, so >=12 loads stay in flight under the compiler's
// own vmcnt placement. launch_bounds(256,2): room for ~135 VGPR, no forced
// spills (r2/r3 lesson), ~3.5 waves/SIMD. Corner loads go back through L1
// (r9 proved nontemporal hurts: real L1 reuse exists).
// Fragment layouts (m89/m120-verified): A[m=lane&15][k=quad*8+j],
// B[k=quad*8+j][n=lane&15], D[row=quad*4+reg][col=lane&15].

#define BB 4
#define CC 64
#define HH 128
#define WW 128
#define OO 64
#define KHW 3
#define KK 9
#define HW (HH * WW)

typedef __bf16 bf16_t;
typedef bf16_t bf16x8 __attribute__((ext_vector_type(8)));
typedef float f32x4 __attribute__((ext_vector_type(4)));

// ---- x (NCHW fp32) -> xt (NHWC bf16), LDS-tiled transpose ----
__global__ __launch_bounds__(256) void nhwc_kernel(const float* __restrict__ x,
                                                   bf16_t* __restrict__ xt) {
    __shared__ float tile[64 * 65];
    const int t  = threadIdx.x;
    const int b  = blockIdx.x >> 8;
    const int p0 = (blockIdx.x & 255) << 6;
#pragma unroll
    for (int i = 0; i < 16; ++i) {
        int c = i * 4 + (t >> 6);
        int p = t & 63;
        tile[c * 65 + p] = x[(b * CC + c) * HW + p0 + p];  // coalesced read
    }
    __syncthreads();
#pragma unroll
    for (int i = 0; i < 16; ++i) {
        int p = i * 4 + (t >> 6);
        int c = t & 63;
        xt[(size_t)((b * HW) + p0 + p) * CC + c] = (bf16_t)tile[c * 65 + p];
    }
}

// ---- weight [O][C][3][3] fp32 -> B-fragment order bf16 ----
// wf element index: ((tap*2+q)*4+nt)*64*8 + lane*8 + j
//   holds W[o = nt*16 + (lane&15)][c = q*32 + (lane>>4)*8 + j][tap]
__global__ void wfrag_kernel(const float* __restrict__ w,
                             bf16_t* __restrict__ wf) {
    int i = blockIdx.x * blockDim.x + threadIdx.x;
    if (i >= OO * CC * KK) return;
    int j    = i & 7;
    int lane = (i >> 3) & 63;
    int nt   = (i >> 9) & 3;
    int q    = (i >> 11) & 1;
    int k    = i >> 12;
    int o = nt * 16 + (lane & 15);
    int c = q * 32 + ((lane >> 4) << 3) + j;
    wf[i] = (bf16_t)w[(o * CC + c) * KK + k];
}

__global__ __launch_bounds__(256, 2) void deform_conv_mfma(
    const bf16_t* __restrict__ xt, const float* __restrict__ offset,
    const float* __restrict__ mask, const bf16x8* __restrict__ wf,
    const float* __restrict__ bias, float* __restrict__ out) {
    const int t     = threadIdx.x;
    const int lane  = t & 63;
    const int wv    = t >> 6;
    const int strip = wv & 1;                  // which 16-pixel strip
    const int half  = wv >> 1;                 // which 32-channel half
    const int b     = blockIdx.x >> 9;         // 512 blocks per image
    const int p0    = (blockIdx.x & 511) << 5; // block's 32-pixel group
    const int m0    = strip << 4;
    const int col   = lane & 15;
    const int quad  = lane >> 4;

    // This lane samples pixel (p0+m0+col), channels half*32 + quad*8 .. +8
    // -- exactly its A-fragment slots for K-chunk `half`.
    const int rem = p0 + m0 + col;
    const int ho  = rem >> 7;
    const int wo  = rem & (WW - 1);
    const int cb  = (half << 5) + (quad << 3);

    const bf16_t* xb = xt + (size_t)b * HW * CC;

    __shared__ f32x4 red[2][4][64];            // [strip][nt][lane], 8 KB

    f32x4 acc[4];
#pragma unroll
    for (int nt = 0; nt < 4; ++nt) acc[nt] = (f32x4){0.f, 0.f, 0.f, 0.f};

    const int offbase = (b * (2 * KK)) * HW + rem;
    const int mbase   = (b * KK) * HW + rem;

    // ---- preload ALL taps' offsets/masks: 27 independent loads in flight --
    float oy[KK], ox[KK], mk[KK];
#pragma unroll
    for (int k = 0; k < KK; ++k) {
        oy[k] = offset[offbase + (2 * k) * HW];
        ox[k] = offset[offbase + (2 * k + 1) * HW];
        mk[k] = mask[mbase + k * HW];
    }

#pragma unroll
    for (int bt = 0; bt < 3; ++bt) {
        // --- phase 1: addr + folded-weight calc for 3 taps (pure VALU) ---
        float W0[3], W1[3], W2[3], W3[3];
        int   O0[3], O1[3], O2[3], O3[3];
#pragma unroll
        for (int j = 0; j < 3; ++j) {
            const int k = bt * 3 + j;
            float py = oy[k] + (float)(k / KHW) + (float)(ho - 1);
            float px = ox[k] + (float)(k % KHW) + (float)(wo - 1);
            float fy0 = floorf(py), fx0 = floorf(px);
            float ly = py - fy0, lx = px - fx0;
            int y0 = (int)fy0, x0 = (int)fx0;
            int y1 = y0 + 1, x1 = x0 + 1;
            bool vy0 = (y0 >= 0) && (y0 < HH);
            bool vy1 = (y1 >= 0) && (y1 < HH);
            bool vx0 = (x0 >= 0) && (x0 < WW);
            bool vx1 = (x1 >= 0) && (x1 < WW);
            int cy0 = min(max(y0, 0), HH - 1), cy1 = min(max(y1, 0), HH - 1);
            int cx0 = min(max(x0, 0), WW - 1), cx1 = min(max(x1, 0), WW - 1);
            float mm = mk[k];
            W0[j] = (vy0 && vx0) ? mm * (1.0f - ly) * (1.0f - lx) : 0.0f;
            W1[j] = (vy0 && vx1) ? mm * (1.0f - ly) * lx : 0.0f;
            W2[j] = (vy1 && vx0) ? mm * ly * (1.0f - lx) : 0.0f;
            W3[j] = (vy1 && vx1) ? mm * ly * lx : 0.0f;
            O0[j] = (cy0 * WW + cx0) * CC + cb;
            O1[j] = (cy0 * WW + cx1) * CC + cb;
            O2[j] = (cy1 * WW + cx0) * CC + cb;
            O3[j] = (cy1 * WW + cx1) * CC + cb;
        }

        // --- phase 2: issue all 12 gathers back-to-back (uniform base +
        //     per-lane int offset); all uses come after all loads ---
        bf16x8 A0[3], A1[3], A2[3], A3[3];
#pragma unroll
        for (int j = 0; j < 3; ++j) {
            A0[j] = *(const bf16x8*)(xb + O0[j]);
            A1[j] = *(const bf16x8*)(xb + O1[j]);
            A2[j] = *(const bf16x8*)(xb + O2[j]);
            A3[j] = *(const bf16x8*)(xb + O3[j]);
        }

        // --- phase 3: interpolate + MFMA per tap ---
#pragma unroll
        for (int j = 0; j < 3; ++j) {
            const int k = bt * 3 + j;
            bf16x8 af;
#pragma unroll
            for (int i = 0; i < 8; ++i) {
                float v = W0[j] * (float)A0[j][i] + W1[j] * (float)A1[j][i] +
                          W2[j] * (float)A2[j][i] + W3[j] * (float)A3[j][i];
                af[i] = (bf16_t)v;
            }
            const bf16x8* wk = wf + (size_t)((k * 2 + half) * 4) * 64;
#pragma unroll
            for (int nt = 0; nt < 4; ++nt) {
                bf16x8 bfr = wk[nt * 64 + lane];
                acc[nt] = __builtin_amdgcn_mfma_f32_16x16x32_bf16(
                    af, bfr, acc[nt], 0, 0, 0);
            }
        }
    }

    // ---- combine channel-halves, then epilogue from half==0 waves ----
    if (half == 1) {
#pragma unroll
        for (int nt = 0; nt < 4; ++nt) red[strip][nt][lane] = acc[nt];
    }
    __syncthreads();
    if (half == 0) {
#pragma unroll
        for (int nt = 0; nt < 4; ++nt) {
            int o = nt * 16 + col;
            float bv = bias[o];
            f32x4 r = acc[nt] + red[strip][nt][lane];
            r.x += bv; r.y += bv; r.z += bv; r.w += bv;
            // D[row=quad*4+reg][col]; row -> pixel, col -> output channel.
            float* dst = out + (size_t)(b * OO + o) * HW + p0 + m0 + quad * 4;
            *(f32x4*)dst = r;  // 4 consecutive pixels, 16B aligned
        }
    }
}

extern "C" void kernel_launch(void* const* d_in, const int* in_sizes, int n_in,
                              void* d_out, int out_size, void* d_ws,
                              size_t ws_size, hipStream_t stream) {
    const float* x      = (const float*)d_in[0];
    const float* offset = (const float*)d_in[1];
    const float* mask   = (const float*)d_in[2];
    const float* weight = (const float*)d_in[3];
    const float* bias   = (const float*)d_in[4];
    float* out = (float*)d_out;

    bf16_t* xt  = (bf16_t*)d_ws;                      // 4*16384*64*2 = 8 MB
    bf16_t* wfr = (bf16_t*)((char*)d_ws + (size_t)BB * HW * CC * 2);  // 72 KB

    nhwc_kernel<<<BB * (HW / 64), 256, 0, stream>>>(x, xt);

    int nw = OO * CC * KK;  // 36864
    wfrag_kernel<<<(nw + 255) / 256, 256, 0, stream>>>(weight, wfr);

    deform_conv_mfma<<<BB * (HW / 32), 256, 0, stream>>>(
        xt, offset, mask, (const bf16x8*)wfr, bias, out);
}